// Round 1
// baseline (2688.960 us; speedup 1.0000x reference)
//
#include <hip/hip_runtime.h>

#define D 128
#define LN_EPS 1e-5f

static constexpr int cN0 = 20000,  cE0 = 100000;
static constexpr int cN1 = 100000, cE1 = 400000;
static constexpr int cN2 = 400000, cE2 = 800000;

// ---------------- CSR / degree build ----------------

__global__ void k_count(const int* __restrict__ src, const int* __restrict__ dst,
                        int* cnt_out, int* cnt_in, int E) {
    int e = blockIdx.x * blockDim.x + threadIdx.x;
    if (e < E) {
        atomicAdd(&cnt_out[src[e]], 1);
        atomicAdd(&cnt_in[dst[e]], 1);
    }
}

// per-block sums of 1024 elements
__global__ void k_bsum(const int* __restrict__ cnt, int* bsum, int n) {
    __shared__ int sd[256];
    int t = threadIdx.x;
    int base = blockIdx.x * 1024 + t * 4;
    int s = 0;
#pragma unroll
    for (int i = 0; i < 4; ++i) { int idx = base + i; if (idx < n) s += cnt[idx]; }
    sd[t] = s; __syncthreads();
    for (int off = 128; off > 0; off >>= 1) {
        if (t < off) sd[t] += sd[t + off];
        __syncthreads();
    }
    if (t == 0) bsum[blockIdx.x] = sd[0];
}

// exclusive scan write: ptr[i] = prefix(cnt)[i]; ptr[n] = E
__global__ void k_scan_write(const int* __restrict__ cnt, const int* __restrict__ bsum,
                             int* __restrict__ ptr, int n, int E) {
    __shared__ int sd[256];
    __shared__ int so[256];
    int t = threadIdx.x, blk = blockIdx.x;
    int off = 0;
    for (int i = t; i < blk; i += 256) off += bsum[i];
    so[t] = off; __syncthreads();
    for (int o = 128; o > 0; o >>= 1) { if (t < o) so[t] += so[t + o]; __syncthreads(); }
    int boff = so[0];
    int base = blk * 1024 + t * 4;
    int vals[4]; int s = 0;
#pragma unroll
    for (int i = 0; i < 4; ++i) { int idx = base + i; vals[i] = (idx < n) ? cnt[idx] : 0; s += vals[i]; }
    sd[t] = s; __syncthreads();
    for (int o = 1; o < 256; o <<= 1) {
        int x = (t >= o) ? sd[t - o] : 0;
        __syncthreads();
        sd[t] += x;
        __syncthreads();
    }
    int run = boff + sd[t] - s;   // exclusive prefix for this thread's chunk
#pragma unroll
    for (int i = 0; i < 4; ++i) {
        int idx = base + i;
        if (idx < n) ptr[idx] = run;
        run += vals[i];
    }
    if (blk == 0 && t == 0) ptr[n] = E;
}

__global__ void k_rin_cursor(const int* __restrict__ cnt_out, const int* __restrict__ cnt_in,
                             const int* __restrict__ ptr, float* __restrict__ rout,
                             float* __restrict__ rin, int* __restrict__ cursor, int n) {
    int i = blockIdx.x * blockDim.x + threadIdx.x;
    if (i < n) {
        rout[i] = rsqrtf((float)(cnt_out[i] + 1));  // +1 self-loop
        rin[i]  = rsqrtf((float)(cnt_in[i] + 1));
        cursor[i] = ptr[i];
    }
}

__global__ void k_fill(const int* __restrict__ dst, int* cursor, int* __restrict__ eid, int E) {
    int e = blockIdx.x * blockDim.x + threadIdx.x;
    if (e < E) {
        int p = atomicAdd(&cursor[dst[e]], 1);
        eid[p] = e;
    }
}

// ---------------- fusion input: td = segment_sum(child_h, dst) via CSR ----------------
// one wave (64 lanes) per node, float2 per lane
__global__ void k_segsum_rows(float* __restrict__ X, const int* __restrict__ ptr,
                              const int* __restrict__ eid, const float* __restrict__ table,
                              int n) {
    int wid = (blockIdx.x * blockDim.x + threadIdx.x) >> 6;
    int lane = threadIdx.x & 63;
    if (wid >= n) return;
    int j = lane * 2;
    float2 acc = make_float2(0.f, 0.f);
    int p0 = ptr[wid], p1 = ptr[wid + 1];
    for (int p = p0; p < p1; ++p) {
        int e = eid[p];
        const float2 x = *(const float2*)(table + (size_t)e * D + j);
        acc.x += x.x; acc.y += x.y;
    }
    *(float2*)(X + (size_t)wid * D + j) = acc;
}

// ---------------- gconv GEMM: HN = (A[ridx] * rout) @ W,  W is [128,128] ----------------
// BM=64, BN=128, BK=16, 256 threads, 8x4 accum per thread
template<bool GATHER>
__global__ __launch_bounds__(256) void k_gconv_gemm(const float* __restrict__ A,
                                                    const int* __restrict__ ridx,
                                                    const float* __restrict__ rs,
                                                    const float* __restrict__ W,
                                                    float* __restrict__ C, int M) {
    __shared__ __align__(16) float As[16][68];   // transposed A tile [k][row]
    __shared__ __align__(16) float Ws[16][128];
    int tid = threadIdx.x;
    int tx = tid & 31, ty = tid >> 5;
    int row0 = blockIdx.x * 64;
    int lr = tid >> 2, lk = (tid & 3) * 4;
    float acc[8][4] = {{0.f}};
    for (int k0 = 0; k0 < 128; k0 += 16) {
        int ar = row0 + lr;
        float4 av = make_float4(0.f, 0.f, 0.f, 0.f);
        float s = 0.f;
        if (ar < M) {
            int sr = GATHER ? ridx[ar] : ar;
            av = *(const float4*)(A + (size_t)sr * 128 + k0 + lk);
            s = rs[ar];
        }
        As[lk + 0][lr] = av.x * s;
        As[lk + 1][lr] = av.y * s;
        As[lk + 2][lr] = av.z * s;
        As[lk + 3][lr] = av.w * s;
        float4 w0 = *(const float4*)(W + (size_t)(k0 + ty) * 128 + tx * 4);
        float4 w1 = *(const float4*)(W + (size_t)(k0 + ty + 8) * 128 + tx * 4);
        *(float4*)&Ws[ty][tx * 4] = w0;
        *(float4*)&Ws[ty + 8][tx * 4] = w1;
        __syncthreads();
#pragma unroll
        for (int k = 0; k < 16; ++k) {
            float4 w = *(const float4*)&Ws[k][tx * 4];
            float4 a0 = *(const float4*)&As[k][ty * 8];
            float4 a1 = *(const float4*)&As[k][ty * 8 + 4];
            float a[8] = {a0.x, a0.y, a0.z, a0.w, a1.x, a1.y, a1.z, a1.w};
#pragma unroll
            for (int i = 0; i < 8; ++i) {
                acc[i][0] += a[i] * w.x;
                acc[i][1] += a[i] * w.y;
                acc[i][2] += a[i] * w.z;
                acc[i][3] += a[i] * w.w;
            }
        }
        __syncthreads();
    }
#pragma unroll
    for (int i = 0; i < 8; ++i) {
        int r = row0 + ty * 8 + i;
        if (r < M)
            *(float4*)(C + (size_t)r * 128 + tx * 4) =
                make_float4(acc[i][0], acc[i][1], acc[i][2], acc[i][3]);
    }
}

// ---------------- aggregation + finalize + relu-concat accumulate ----------------
// one wave per node: acc = HN[v] + sum_e HN[src[eid]]; v = (acc*rin + b) * cw
// RES[v][0:128] (+)= relu(v); RES[v][128:256] (+)= v
__global__ void k_agg_res(const float* __restrict__ HN, const int* __restrict__ ptr,
                          const int* __restrict__ eid, const int* __restrict__ src,
                          const float* __restrict__ rin, const float* __restrict__ b,
                          const float* __restrict__ cw, float* __restrict__ RES,
                          int n, int accum) {
    int wid = (blockIdx.x * blockDim.x + threadIdx.x) >> 6;
    int lane = threadIdx.x & 63;
    if (wid >= n) return;
    int j = lane * 2;
    float2 acc = *(const float2*)(HN + (size_t)wid * D + j);  // self-loop
    int p0 = ptr[wid], p1 = ptr[wid + 1];
    for (int p = p0; p < p1; ++p) {
        int s = src[eid[p]];
        const float2 x = *(const float2*)(HN + (size_t)s * D + j);
        acc.x += x.x; acc.y += x.y;
    }
    float ri = rin[wid];
    float vx = (acc.x * ri + b[j]) * cw[j];
    float vy = (acc.y * ri + b[j + 1]) * cw[j + 1];
    float rx = fmaxf(vx, 0.f), ry = fmaxf(vy, 0.f);
    float* r = RES + (size_t)wid * (2 * D) + j;
    if (accum) {
        r[0] += rx; r[1] += ry; r[D] += vx; r[D + 1] += vy;
    } else {
        r[0] = rx; r[1] = ry; r[D] = vx; r[D + 1] = vy;
    }
}

// ---------------- cat projection + LayerNorm: out = LN(RES @ catW + catb) * g + be ----------------
__global__ __launch_bounds__(256) void k_gemm_cat_ln(const float* __restrict__ A,
                                                     const float* __restrict__ W,
                                                     const float* __restrict__ bias,
                                                     const float* __restrict__ g,
                                                     const float* __restrict__ be,
                                                     float* __restrict__ out, int M) {
    __shared__ __align__(16) float As[16][68];
    __shared__ __align__(16) float Ws[16][128];
    int tid = threadIdx.x;
    int tx = tid & 31, ty = tid >> 5;
    int row0 = blockIdx.x * 64;
    int lr = tid >> 2, lk = (tid & 3) * 4;
    float acc[8][4] = {{0.f}};
    for (int k0 = 0; k0 < 256; k0 += 16) {
        int ar = row0 + lr;
        float4 av = make_float4(0.f, 0.f, 0.f, 0.f);
        if (ar < M) av = *(const float4*)(A + (size_t)ar * 256 + k0 + lk);
        As[lk + 0][lr] = av.x;
        As[lk + 1][lr] = av.y;
        As[lk + 2][lr] = av.z;
        As[lk + 3][lr] = av.w;
        float4 w0 = *(const float4*)(W + (size_t)(k0 + ty) * 128 + tx * 4);
        float4 w1 = *(const float4*)(W + (size_t)(k0 + ty + 8) * 128 + tx * 4);
        *(float4*)&Ws[ty][tx * 4] = w0;
        *(float4*)&Ws[ty + 8][tx * 4] = w1;
        __syncthreads();
#pragma unroll
        for (int k = 0; k < 16; ++k) {
            float4 w = *(const float4*)&Ws[k][tx * 4];
            float4 a0 = *(const float4*)&As[k][ty * 8];
            float4 a1 = *(const float4*)&As[k][ty * 8 + 4];
            float a[8] = {a0.x, a0.y, a0.z, a0.w, a1.x, a1.y, a1.z, a1.w};
#pragma unroll
            for (int i = 0; i < 8; ++i) {
                acc[i][0] += a[i] * w.x;
                acc[i][1] += a[i] * w.y;
                acc[i][2] += a[i] * w.z;
                acc[i][3] += a[i] * w.w;
            }
        }
        __syncthreads();
    }
    float4 bv = *(const float4*)(bias + tx * 4);
    float4 gv = *(const float4*)(g + tx * 4);
    float4 ev = *(const float4*)(be + tx * 4);
#pragma unroll
    for (int i = 0; i < 8; ++i) {
        float x0 = acc[i][0] + bv.x, x1 = acc[i][1] + bv.y;
        float x2 = acc[i][2] + bv.z, x3 = acc[i][3] + bv.w;
        float sum = x0 + x1 + x2 + x3;
        float ss = x0 * x0 + x1 * x1 + x2 * x2 + x3 * x3;
#pragma unroll
        for (int m = 1; m <= 16; m <<= 1) {
            sum += __shfl_xor(sum, m, 64);
            ss  += __shfl_xor(ss, m, 64);
        }
        float mu = sum * (1.0f / 128.0f);
        float var = ss * (1.0f / 128.0f) - mu * mu;
        float inv = rsqrtf(var + LN_EPS);
        int r = row0 + ty * 8 + i;
        if (r < M) {
            float4 o;
            o.x = (x0 - mu) * inv * gv.x + ev.x;
            o.y = (x1 - mu) * inv * gv.y + ev.y;
            o.z = (x2 - mu) * inv * gv.z + ev.z;
            o.w = (x3 - mu) * inv * gv.w + ev.w;
            *(float4*)(out + (size_t)r * 128 + tx * 4) = o;
        }
    }
}

__global__ void k_ws_too_small(float* out) {
    if (threadIdx.x == 0 && blockIdx.x == 0) out[0] = 12345678.f;
}

// ---------------- orchestration ----------------

struct Lvl {
    int n, E;
    const int *src, *dst;
    int *cnt_out, *cnt_in, *ptr, *cursor, *eid;
    float *rout, *rin;
};

static inline char* bump(char*& p, size_t bytes, void** out) {
    *out = (void*)p;
    p += (bytes + 255) & ~(size_t)255;
    return p;
}

extern "C" void kernel_launch(void* const* d_in, const int* in_sizes, int n_in,
                              void* d_out, int out_size, void* d_ws, size_t ws_size,
                              hipStream_t stream) {
    const float* h0 = (const float*)d_in[0];
    const float* h1 = (const float*)d_in[1];
    const float* h2 = (const float*)d_in[2];
    const int* src0 = (const int*)d_in[3];
    const int* dst0 = (const int*)d_in[4];
    const int* src1 = (const int*)d_in[5];
    const int* dst1 = (const int*)d_in[6];
    const int* src2 = (const int*)d_in[7];
    const int* dst2 = (const int*)d_in[8];
    const float* convW = (const float*)d_in[9];
    const float* convb = (const float*)d_in[10];
    const float* fusW  = (const float*)d_in[11];
    const float* fusb  = (const float*)d_in[12];
    const float* catW  = (const float*)d_in[13];
    const float* catb  = (const float*)d_in[14];
    const float* convw = (const float*)d_in[15];
    const float* tdw   = (const float*)d_in[16];
    const float* buw   = (const float*)d_in[17];
    const float* lng   = (const float*)d_in[18];
    const float* lnb   = (const float*)d_in[19];
    float* out = (float*)d_out;

    // workspace carve-out
    char* p = (char*)d_ws;
    void *vX, *vHN, *vRES, *vbsum;
    bump(p, (size_t)cN1 * D * 4, &vX);        // X only needed for td inputs (levels 0,1)
    bump(p, (size_t)cN2 * D * 4, &vHN);
    bump(p, (size_t)cN2 * 2 * D * 4, &vRES);
    bump(p, 512 * 4, &vbsum);
    float* X = (float*)vX;
    float* HN = (float*)vHN;
    float* RES = (float*)vRES;
    int* bsum = (int*)vbsum;

    Lvl lv[3];
    lv[0] = {cN0, cE0, src0, dst0};
    lv[1] = {cN1, cE1, src1, dst1};
    lv[2] = {cN2, cE2, src2, dst2};
    for (int L = 0; L < 3; ++L) {
        Lvl& v = lv[L];
        void* t;
        bump(p, (size_t)v.n * 4, &t);       v.cnt_out = (int*)t;
        bump(p, (size_t)v.n * 4, &t);       v.cnt_in  = (int*)t;
        bump(p, (size_t)(v.n + 1) * 4, &t); v.ptr     = (int*)t;
        bump(p, (size_t)v.n * 4, &t);       v.cursor  = (int*)t;
        bump(p, (size_t)v.E * 4, &t);       v.eid     = (int*)t;
        bump(p, (size_t)v.n * 4, &t);       v.rout    = (float*)t;
        bump(p, (size_t)v.n * 4, &t);       v.rin     = (float*)t;
    }
    size_t need = (size_t)(p - (char*)d_ws);
    if (need > ws_size) {
        hipLaunchKernelGGL(k_ws_too_small, dim3(1), dim3(64), 0, stream, out);
        return;
    }

    // CSR + degree build per level
    for (int L = 0; L < 3; ++L) {
        Lvl& v = lv[L];
        hipMemsetAsync(v.cnt_out, 0, (size_t)v.n * 4, stream);
        hipMemsetAsync(v.cnt_in, 0, (size_t)v.n * 4, stream);
        k_count<<<(v.E + 255) / 256, 256, 0, stream>>>(v.src, v.dst, v.cnt_out, v.cnt_in, v.E);
        int nb = (v.n + 1023) / 1024;
        k_bsum<<<nb, 256, 0, stream>>>(v.cnt_in, bsum, v.n);
        k_scan_write<<<nb, 256, 0, stream>>>(v.cnt_in, bsum, v.ptr, v.n, v.E);
        k_rin_cursor<<<(v.n + 255) / 256, 256, 0, stream>>>(v.cnt_out, v.cnt_in, v.ptr,
                                                            v.rout, v.rin, v.cursor, v.n);
        k_fill<<<(v.E + 255) / 256, 256, 0, stream>>>(v.dst, v.cursor, v.eid, v.E);
    }

    auto gconv = [&](int L, const float* A, const int* ridx, const float* W,
                     const float* b, const float* cw, int accum) {
        Lvl& v = lv[L];
        if (ridx)
            k_gconv_gemm<true><<<(v.n + 63) / 64, 256, 0, stream>>>(A, ridx, v.rout, W, HN, v.n);
        else
            k_gconv_gemm<false><<<(v.n + 63) / 64, 256, 0, stream>>>(A, nullptr, v.rout, W, HN, v.n);
        k_agg_res<<<(v.n + 3) / 4, 256, 0, stream>>>(HN, v.ptr, v.eid, v.src, v.rin,
                                                     b, cw, RES, v.n, accum);
    };

    // ---- level 0 (params idx 0): conv(h0) + td0 = segsum(h1 over dst0) ----
    gconv(0, h0, nullptr, convW + 0, convb + 0, convw + 0, 0);
    k_segsum_rows<<<(cN0 + 3) / 4, 256, 0, stream>>>(X, lv[0].ptr, lv[0].eid, h1, cN0);
    gconv(0, X, nullptr, fusW + 0, fusb + 0, tdw + 0, 1);
    k_gemm_cat_ln<<<(cN0 + 63) / 64, 256, 0, stream>>>(RES, catW + 0, catb + 0,
                                                       lng + 0, lnb + 0, out, cN0);

    // ---- level 1 (params idx 2): conv(h1) + bu1 = h0[dst0] + td1 = segsum(h2 over dst1) ----
    gconv(1, h1, nullptr, convW + 2 * D * D, convb + 2 * D, convw + 2 * D, 0);
    gconv(1, h0, dst0, fusW + 2 * D * D, fusb + 2 * D, buw + 2 * D, 1);   // bu1 gathered in-GEMM
    k_segsum_rows<<<(cN1 + 3) / 4, 256, 0, stream>>>(X, lv[1].ptr, lv[1].eid, h2, cN1);
    gconv(1, X, nullptr, fusW + 2 * D * D, fusb + 2 * D, tdw + 2 * D, 1);
    k_gemm_cat_ln<<<(cN1 + 63) / 64, 256, 0, stream>>>(RES, catW + 2 * 2 * D * D, catb + 2 * D,
                                                       lng + 2 * D, lnb + 2 * D,
                                                       out + (size_t)cN0 * D, cN1);

    // ---- level 2 (params idx 1): conv(h2) + bu2 = h1[dst1] ----
    gconv(2, h2, nullptr, convW + 1 * D * D, convb + 1 * D, convw + 1 * D, 0);
    gconv(2, h1, dst1, fusW + 1 * D * D, fusb + 1 * D, buw + 1 * D, 1);   // bu2 gathered in-GEMM
    k_gemm_cat_ln<<<(cN2 + 63) / 64, 256, 0, stream>>>(RES, catW + 1 * 2 * D * D, catb + 1 * D,
                                                       lng + 1 * D, lnb + 1 * D,
                                                       out + (size_t)(cN0 + cN1) * D, cN2);
}

// Round 2
// 1990.233 us; speedup vs baseline: 1.3511x; 1.3511x over previous
//
#include <hip/hip_runtime.h>

#define D 128
#define LN_EPS 1e-5f

static constexpr int cN0 = 20000,  cE0 = 100000;
static constexpr int cN1 = 100000, cE1 = 400000;
static constexpr int cN2 = 400000, cE2 = 800000;

// ---------------- bf16 helpers ----------------
__device__ inline float bf2f(unsigned short u) {
    unsigned int x = ((unsigned int)u) << 16;
    return __builtin_bit_cast(float, x);
}
__device__ inline unsigned short f2bf(float f) {
    unsigned int u = __builtin_bit_cast(unsigned int, f);
    unsigned int r = (u + 0x7FFFu + ((u >> 16) & 1u)) >> 16;  // RN-even
    return (unsigned short)r;
}
__device__ inline float4 bf4_to_f4(ushort4 v) {
    return make_float4(bf2f(v.x), bf2f(v.y), bf2f(v.z), bf2f(v.w));
}

// ---------------- CSR / degree build ----------------

__global__ void k_count(const int* __restrict__ src, const int* __restrict__ dst,
                        int* cnt_out, int* cnt_in, int E) {
    int e = blockIdx.x * blockDim.x + threadIdx.x;
    if (e < E) {
        atomicAdd(&cnt_out[src[e]], 1);
        atomicAdd(&cnt_in[dst[e]], 1);
    }
}

__global__ void k_bsum(const int* __restrict__ cnt, int* bsum, int n) {
    __shared__ int sd[256];
    int t = threadIdx.x;
    int base = blockIdx.x * 1024 + t * 4;
    int s = 0;
#pragma unroll
    for (int i = 0; i < 4; ++i) { int idx = base + i; if (idx < n) s += cnt[idx]; }
    sd[t] = s; __syncthreads();
    for (int off = 128; off > 0; off >>= 1) {
        if (t < off) sd[t] += sd[t + off];
        __syncthreads();
    }
    if (t == 0) bsum[blockIdx.x] = sd[0];
}

__global__ void k_scan_write(const int* __restrict__ cnt, const int* __restrict__ bsum,
                             int* __restrict__ ptr, int n, int E) {
    __shared__ int sd[256];
    __shared__ int so[256];
    int t = threadIdx.x, blk = blockIdx.x;
    int off = 0;
    for (int i = t; i < blk; i += 256) off += bsum[i];
    so[t] = off; __syncthreads();
    for (int o = 128; o > 0; o >>= 1) { if (t < o) so[t] += so[t + o]; __syncthreads(); }
    int boff = so[0];
    int base = blk * 1024 + t * 4;
    int vals[4]; int s = 0;
#pragma unroll
    for (int i = 0; i < 4; ++i) { int idx = base + i; vals[i] = (idx < n) ? cnt[idx] : 0; s += vals[i]; }
    sd[t] = s; __syncthreads();
    for (int o = 1; o < 256; o <<= 1) {
        int x = (t >= o) ? sd[t - o] : 0;
        __syncthreads();
        sd[t] += x;
        __syncthreads();
    }
    int run = boff + sd[t] - s;
#pragma unroll
    for (int i = 0; i < 4; ++i) {
        int idx = base + i;
        if (idx < n) ptr[idx] = run;
        run += vals[i];
    }
    if (blk == 0 && t == 0) ptr[n] = E;
}

__global__ void k_rin_cursor(const int* __restrict__ cnt_out, const int* __restrict__ cnt_in,
                             const int* __restrict__ ptr, float* __restrict__ rout,
                             float* __restrict__ rin, int* __restrict__ cursor, int n) {
    int i = blockIdx.x * blockDim.x + threadIdx.x;
    if (i < n) {
        rout[i] = rsqrtf((float)(cnt_out[i] + 1));  // +1 self-loop
        rin[i]  = rsqrtf((float)(cnt_in[i] + 1));
        cursor[i] = ptr[i];
    }
}

// fill CSR adjacency: both edge id (for segsum) and source node id (for agg)
__global__ void k_fill(const int* __restrict__ src, const int* __restrict__ dst,
                       int* cursor, int* __restrict__ eid, int* __restrict__ srcs, int E) {
    int e = blockIdx.x * blockDim.x + threadIdx.x;
    if (e < E) {
        int p = atomicAdd(&cursor[dst[e]], 1);
        eid[p] = e;
        srcs[p] = src[e];
    }
}

// ---------------- fusion input: td = segment_sum(child_h, dst) via CSR ----------------
__global__ void k_segsum_rows(float* __restrict__ X, const int* __restrict__ ptr,
                              const int* __restrict__ eid, const float* __restrict__ table,
                              int n) {
    int wid = (blockIdx.x * blockDim.x + threadIdx.x) >> 6;
    int lane = threadIdx.x & 63;
    if (wid >= n) return;
    int j = lane * 2;
    float2 acc = make_float2(0.f, 0.f);
    int p0 = ptr[wid], p1 = ptr[wid + 1];
    for (int p = p0; p < p1; ++p) {
        int e = eid[p];
        const float2 x = *(const float2*)(table + (size_t)e * D + j);
        acc.x += x.x; acc.y += x.y;
    }
    *(float2*)(X + (size_t)wid * D + j) = acc;
}

// ---------------- gconv GEMM: HN(bf16) = (A[ridx] * rout) @ W ----------------
template<bool GATHER>
__global__ __launch_bounds__(256) void k_gconv_gemm(const float* __restrict__ A,
                                                    const int* __restrict__ ridx,
                                                    const float* __restrict__ rs,
                                                    const float* __restrict__ W,
                                                    unsigned short* __restrict__ C, int M) {
    __shared__ __align__(16) float As[16][68];
    __shared__ __align__(16) float Ws[16][128];
    int tid = threadIdx.x;
    int tx = tid & 31, ty = tid >> 5;
    int row0 = blockIdx.x * 64;
    int lr = tid >> 2, lk = (tid & 3) * 4;
    float acc[8][4] = {{0.f}};
    for (int k0 = 0; k0 < 128; k0 += 16) {
        int ar = row0 + lr;
        float4 av = make_float4(0.f, 0.f, 0.f, 0.f);
        float s = 0.f;
        if (ar < M) {
            int sr = GATHER ? ridx[ar] : ar;
            av = *(const float4*)(A + (size_t)sr * 128 + k0 + lk);
            s = rs[ar];
        }
        As[lk + 0][lr] = av.x * s;
        As[lk + 1][lr] = av.y * s;
        As[lk + 2][lr] = av.z * s;
        As[lk + 3][lr] = av.w * s;
        float4 w0 = *(const float4*)(W + (size_t)(k0 + ty) * 128 + tx * 4);
        float4 w1 = *(const float4*)(W + (size_t)(k0 + ty + 8) * 128 + tx * 4);
        *(float4*)&Ws[ty][tx * 4] = w0;
        *(float4*)&Ws[ty + 8][tx * 4] = w1;
        __syncthreads();
#pragma unroll
        for (int k = 0; k < 16; ++k) {
            float4 w = *(const float4*)&Ws[k][tx * 4];
            float4 a0 = *(const float4*)&As[k][ty * 8];
            float4 a1 = *(const float4*)&As[k][ty * 8 + 4];
            float a[8] = {a0.x, a0.y, a0.z, a0.w, a1.x, a1.y, a1.z, a1.w};
#pragma unroll
            for (int i = 0; i < 8; ++i) {
                acc[i][0] += a[i] * w.x;
                acc[i][1] += a[i] * w.y;
                acc[i][2] += a[i] * w.z;
                acc[i][3] += a[i] * w.w;
            }
        }
        __syncthreads();
    }
#pragma unroll
    for (int i = 0; i < 8; ++i) {
        int r = row0 + ty * 8 + i;
        if (r < M) {
            ushort4 o;
            o.x = f2bf(acc[i][0]); o.y = f2bf(acc[i][1]);
            o.z = f2bf(acc[i][2]); o.w = f2bf(acc[i][3]);
            *(ushort4*)(C + (size_t)r * 128 + tx * 4) = o;
        }
    }
}

// ---------------- one-pass multi-term aggregation + relu-concat ----------------
// 32 lanes per node (4 cols each), 2 nodes per wave, 8 nodes per 256-block.
// For each term t: v_t = ((HN_t[v] + sum_edges HN_t[srcs]) * rin + b_t) * cw_t
// RES[v][0:128] = sum_t relu(v_t);  RES[v][128:256] = sum_t v_t
template<int NT>
__global__ void k_agg_multi(const unsigned short* __restrict__ H0,
                            const unsigned short* __restrict__ H1,
                            const unsigned short* __restrict__ H2,
                            const int* __restrict__ ptr, const int* __restrict__ srcs,
                            const float* __restrict__ rin,
                            const float* __restrict__ b0, const float* __restrict__ b1,
                            const float* __restrict__ b2,
                            const float* __restrict__ c0, const float* __restrict__ c1,
                            const float* __restrict__ c2,
                            float* __restrict__ RES, int n) {
    int node = (blockIdx.x * blockDim.x + threadIdx.x) >> 5;
    int lane = threadIdx.x & 31;
    if (node >= n) return;
    int j = lane * 4;

    float4 a0 = make_float4(0.f, 0.f, 0.f, 0.f), a1 = a0, a2 = a0;
    // self-loop term
    a0 = bf4_to_f4(*(const ushort4*)(H0 + (size_t)node * D + j));
    if (NT > 1) a1 = bf4_to_f4(*(const ushort4*)(H1 + (size_t)node * D + j));
    if (NT > 2) a2 = bf4_to_f4(*(const ushort4*)(H2 + (size_t)node * D + j));

    int p0 = ptr[node], p1 = ptr[node + 1];
    for (int p = p0; p < p1; ++p) {
        int s = srcs[p];
        float4 x0 = bf4_to_f4(*(const ushort4*)(H0 + (size_t)s * D + j));
        a0.x += x0.x; a0.y += x0.y; a0.z += x0.z; a0.w += x0.w;
        if (NT > 1) {
            float4 x1 = bf4_to_f4(*(const ushort4*)(H1 + (size_t)s * D + j));
            a1.x += x1.x; a1.y += x1.y; a1.z += x1.z; a1.w += x1.w;
        }
        if (NT > 2) {
            float4 x2 = bf4_to_f4(*(const ushort4*)(H2 + (size_t)s * D + j));
            a2.x += x2.x; a2.y += x2.y; a2.z += x2.z; a2.w += x2.w;
        }
    }

    float ri = rin[node];
    float4 bb0 = *(const float4*)(b0 + j);
    float4 cc0 = *(const float4*)(c0 + j);
    float4 v, rsum, ssum;
    v.x = (a0.x * ri + bb0.x) * cc0.x;
    v.y = (a0.y * ri + bb0.y) * cc0.y;
    v.z = (a0.z * ri + bb0.z) * cc0.z;
    v.w = (a0.w * ri + bb0.w) * cc0.w;
    rsum = make_float4(fmaxf(v.x, 0.f), fmaxf(v.y, 0.f), fmaxf(v.z, 0.f), fmaxf(v.w, 0.f));
    ssum = v;
    if (NT > 1) {
        float4 bb = *(const float4*)(b1 + j);
        float4 cc = *(const float4*)(c1 + j);
        v.x = (a1.x * ri + bb.x) * cc.x;
        v.y = (a1.y * ri + bb.y) * cc.y;
        v.z = (a1.z * ri + bb.z) * cc.z;
        v.w = (a1.w * ri + bb.w) * cc.w;
        rsum.x += fmaxf(v.x, 0.f); rsum.y += fmaxf(v.y, 0.f);
        rsum.z += fmaxf(v.z, 0.f); rsum.w += fmaxf(v.w, 0.f);
        ssum.x += v.x; ssum.y += v.y; ssum.z += v.z; ssum.w += v.w;
    }
    if (NT > 2) {
        float4 bb = *(const float4*)(b2 + j);
        float4 cc = *(const float4*)(c2 + j);
        v.x = (a2.x * ri + bb.x) * cc.x;
        v.y = (a2.y * ri + bb.y) * cc.y;
        v.z = (a2.z * ri + bb.z) * cc.z;
        v.w = (a2.w * ri + bb.w) * cc.w;
        rsum.x += fmaxf(v.x, 0.f); rsum.y += fmaxf(v.y, 0.f);
        rsum.z += fmaxf(v.z, 0.f); rsum.w += fmaxf(v.w, 0.f);
        ssum.x += v.x; ssum.y += v.y; ssum.z += v.z; ssum.w += v.w;
    }
    float* r = RES + (size_t)node * (2 * D) + j;
    *(float4*)r = rsum;
    *(float4*)(r + D) = ssum;
}

// ---------------- cat projection + LayerNorm ----------------
__global__ __launch_bounds__(256) void k_gemm_cat_ln(const float* __restrict__ A,
                                                     const float* __restrict__ W,
                                                     const float* __restrict__ bias,
                                                     const float* __restrict__ g,
                                                     const float* __restrict__ be,
                                                     float* __restrict__ out, int M) {
    __shared__ __align__(16) float As[16][68];
    __shared__ __align__(16) float Ws[16][128];
    int tid = threadIdx.x;
    int tx = tid & 31, ty = tid >> 5;
    int row0 = blockIdx.x * 64;
    int lr = tid >> 2, lk = (tid & 3) * 4;
    float acc[8][4] = {{0.f}};
    for (int k0 = 0; k0 < 256; k0 += 16) {
        int ar = row0 + lr;
        float4 av = make_float4(0.f, 0.f, 0.f, 0.f);
        if (ar < M) av = *(const float4*)(A + (size_t)ar * 256 + k0 + lk);
        As[lk + 0][lr] = av.x;
        As[lk + 1][lr] = av.y;
        As[lk + 2][lr] = av.z;
        As[lk + 3][lr] = av.w;
        float4 w0 = *(const float4*)(W + (size_t)(k0 + ty) * 128 + tx * 4);
        float4 w1 = *(const float4*)(W + (size_t)(k0 + ty + 8) * 128 + tx * 4);
        *(float4*)&Ws[ty][tx * 4] = w0;
        *(float4*)&Ws[ty + 8][tx * 4] = w1;
        __syncthreads();
#pragma unroll
        for (int k = 0; k < 16; ++k) {
            float4 w = *(const float4*)&Ws[k][tx * 4];
            float4 a0 = *(const float4*)&As[k][ty * 8];
            float4 a1 = *(const float4*)&As[k][ty * 8 + 4];
            float a[8] = {a0.x, a0.y, a0.z, a0.w, a1.x, a1.y, a1.z, a1.w};
#pragma unroll
            for (int i = 0; i < 8; ++i) {
                acc[i][0] += a[i] * w.x;
                acc[i][1] += a[i] * w.y;
                acc[i][2] += a[i] * w.z;
                acc[i][3] += a[i] * w.w;
            }
        }
        __syncthreads();
    }
    float4 bv = *(const float4*)(bias + tx * 4);
    float4 gv = *(const float4*)(g + tx * 4);
    float4 ev = *(const float4*)(be + tx * 4);
#pragma unroll
    for (int i = 0; i < 8; ++i) {
        float x0 = acc[i][0] + bv.x, x1 = acc[i][1] + bv.y;
        float x2 = acc[i][2] + bv.z, x3 = acc[i][3] + bv.w;
        float sum = x0 + x1 + x2 + x3;
        float ss = x0 * x0 + x1 * x1 + x2 * x2 + x3 * x3;
#pragma unroll
        for (int m = 1; m <= 16; m <<= 1) {
            sum += __shfl_xor(sum, m, 64);
            ss  += __shfl_xor(ss, m, 64);
        }
        float mu = sum * (1.0f / 128.0f);
        float var = ss * (1.0f / 128.0f) - mu * mu;
        float inv = rsqrtf(var + LN_EPS);
        int r = row0 + ty * 8 + i;
        if (r < M) {
            float4 o;
            o.x = (x0 - mu) * inv * gv.x + ev.x;
            o.y = (x1 - mu) * inv * gv.y + ev.y;
            o.z = (x2 - mu) * inv * gv.z + ev.z;
            o.w = (x3 - mu) * inv * gv.w + ev.w;
            *(float4*)(out + (size_t)r * 128 + tx * 4) = o;
        }
    }
}

__global__ void k_ws_too_small(float* out) {
    if (threadIdx.x == 0 && blockIdx.x == 0) out[0] = 12345678.f;
}

// ---------------- orchestration ----------------

struct Lvl {
    int n, E;
    const int *src, *dst;
    int *cnt_out, *cnt_in, *ptr, *cursor, *eid, *srcs;
    float *rout, *rin;
};

static inline char* bump(char*& p, size_t bytes, void** out) {
    *out = (void*)p;
    p += (bytes + 255) & ~(size_t)255;
    return p;
}

extern "C" void kernel_launch(void* const* d_in, const int* in_sizes, int n_in,
                              void* d_out, int out_size, void* d_ws, size_t ws_size,
                              hipStream_t stream) {
    const float* h0 = (const float*)d_in[0];
    const float* h1 = (const float*)d_in[1];
    const float* h2 = (const float*)d_in[2];
    const int* src0 = (const int*)d_in[3];
    const int* dst0 = (const int*)d_in[4];
    const int* src1 = (const int*)d_in[5];
    const int* dst1 = (const int*)d_in[6];
    const int* src2 = (const int*)d_in[7];
    const int* dst2 = (const int*)d_in[8];
    const float* convW = (const float*)d_in[9];
    const float* convb = (const float*)d_in[10];
    const float* fusW  = (const float*)d_in[11];
    const float* fusb  = (const float*)d_in[12];
    const float* catW  = (const float*)d_in[13];
    const float* catb  = (const float*)d_in[14];
    const float* convw = (const float*)d_in[15];
    const float* tdw   = (const float*)d_in[16];
    const float* buw   = (const float*)d_in[17];
    const float* lng   = (const float*)d_in[18];
    const float* lnb   = (const float*)d_in[19];
    float* out = (float*)d_out;

    // workspace carve-out
    char* p = (char*)d_ws;
    void *vX, *vHNa, *vHNb, *vHNc, *vRES, *vbsum;
    bump(p, (size_t)cN1 * D * 4, &vX);            // fp32 td staging (levels 0,1)
    bump(p, (size_t)cN2 * D * 2, &vHNa);          // bf16 HN term a
    bump(p, (size_t)cN2 * D * 2, &vHNb);          // bf16 HN term b
    bump(p, (size_t)cN1 * D * 2, &vHNc);          // bf16 HN term c (level 1 only)
    bump(p, (size_t)cN2 * 2 * D * 4, &vRES);      // fp32 relu-concat result
    bump(p, 512 * 4, &vbsum);
    float* X = (float*)vX;
    unsigned short* HNa = (unsigned short*)vHNa;
    unsigned short* HNb = (unsigned short*)vHNb;
    unsigned short* HNc = (unsigned short*)vHNc;
    float* RES = (float*)vRES;
    int* bsum = (int*)vbsum;

    Lvl lv[3];
    lv[0] = {cN0, cE0, src0, dst0};
    lv[1] = {cN1, cE1, src1, dst1};
    lv[2] = {cN2, cE2, src2, dst2};
    for (int L = 0; L < 3; ++L) {
        Lvl& v = lv[L];
        void* t;
        bump(p, (size_t)v.n * 4, &t);       v.cnt_out = (int*)t;
        bump(p, (size_t)v.n * 4, &t);       v.cnt_in  = (int*)t;
        bump(p, (size_t)(v.n + 1) * 4, &t); v.ptr     = (int*)t;
        bump(p, (size_t)v.n * 4, &t);       v.cursor  = (int*)t;
        bump(p, (size_t)v.E * 4, &t);       v.eid     = (int*)t;
        bump(p, (size_t)v.E * 4, &t);       v.srcs    = (int*)t;
        bump(p, (size_t)v.n * 4, &t);       v.rout    = (float*)t;
        bump(p, (size_t)v.n * 4, &t);       v.rin     = (float*)t;
    }
    size_t need = (size_t)(p - (char*)d_ws);
    if (need > ws_size) {
        hipLaunchKernelGGL(k_ws_too_small, dim3(1), dim3(64), 0, stream, out);
        return;
    }

    for (int L = 0; L < 3; ++L) {
        Lvl& v = lv[L];
        hipMemsetAsync(v.cnt_out, 0, (size_t)v.n * 4, stream);
        hipMemsetAsync(v.cnt_in, 0, (size_t)v.n * 4, stream);
        k_count<<<(v.E + 255) / 256, 256, 0, stream>>>(v.src, v.dst, v.cnt_out, v.cnt_in, v.E);
        int nb = (v.n + 1023) / 1024;
        k_bsum<<<nb, 256, 0, stream>>>(v.cnt_in, bsum, v.n);
        k_scan_write<<<nb, 256, 0, stream>>>(v.cnt_in, bsum, v.ptr, v.n, v.E);
        k_rin_cursor<<<(v.n + 255) / 256, 256, 0, stream>>>(v.cnt_out, v.cnt_in, v.ptr,
                                                            v.rout, v.rin, v.cursor, v.n);
        k_fill<<<(v.E + 255) / 256, 256, 0, stream>>>(v.src, v.dst, v.cursor, v.eid, v.srcs, v.E);
    }

    auto gemm = [&](int L, const float* A, const int* ridx, const float* W, unsigned short* HN) {
        Lvl& v = lv[L];
        if (ridx)
            k_gconv_gemm<true><<<(v.n + 63) / 64, 256, 0, stream>>>(A, ridx, v.rout, W, HN, v.n);
        else
            k_gconv_gemm<false><<<(v.n + 63) / 64, 256, 0, stream>>>(A, nullptr, v.rout, W, HN, v.n);
    };

    // ---- level 0 (params idx 0): conv(h0) + td0 = segsum(h1 over dst0) ----
    {
        Lvl& v = lv[0];
        gemm(0, h0, nullptr, convW + 0, HNa);
        k_segsum_rows<<<(cN0 + 3) / 4, 256, 0, stream>>>(X, v.ptr, v.eid, h1, cN0);
        gemm(0, X, nullptr, fusW + 0, HNb);
        k_agg_multi<2><<<(cN0 * 32 + 255) / 256, 256, 0, stream>>>(
            HNa, HNb, HNa, v.ptr, v.srcs, v.rin,
            convb + 0, fusb + 0, convb + 0,
            convw + 0, tdw + 0, convw + 0, RES, cN0);
        k_gemm_cat_ln<<<(cN0 + 63) / 64, 256, 0, stream>>>(RES, catW + 0, catb + 0,
                                                           lng + 0, lnb + 0, out, cN0);
    }

    // ---- level 1 (params idx 2): conv(h1) + bu1 = h0[dst0] + td1 = segsum(h2 over dst1) ----
    {
        Lvl& v = lv[1];
        const int o1 = 2 * D, o2 = 2 * D * D, o4 = 2 * 2 * D * D;
        gemm(1, h1, nullptr, convW + o2, HNa);
        gemm(1, h0, dst0, fusW + o2, HNb);    // bu1 gathered in-GEMM
        k_segsum_rows<<<(cN1 + 3) / 4, 256, 0, stream>>>(X, v.ptr, v.eid, h2, cN1);
        gemm(1, X, nullptr, fusW + o2, HNc);
        k_agg_multi<3><<<(cN1 * 32 + 255) / 256, 256, 0, stream>>>(
            HNa, HNb, HNc, v.ptr, v.srcs, v.rin,
            convb + o1, fusb + o1, fusb + o1,
            convw + o1, buw + o1, tdw + o1, RES, cN1);
        k_gemm_cat_ln<<<(cN1 + 63) / 64, 256, 0, stream>>>(RES, catW + o4, catb + o1,
                                                           lng + o1, lnb + o1,
                                                           out + (size_t)cN0 * D, cN1);
    }

    // ---- level 2 (params idx 1): conv(h2) + bu2 = h1[dst1] ----
    {
        Lvl& v = lv[2];
        const int o1 = 1 * D, o2 = 1 * D * D, o4 = 1 * 2 * D * D;
        gemm(2, h2, nullptr, convW + o2, HNa);
        gemm(2, h1, dst1, fusW + o2, HNb);    // bu2 gathered in-GEMM
        k_agg_multi<2><<<(cN2 * 32 + 255) / 256, 256, 0, stream>>>(
            HNa, HNb, HNa, v.ptr, v.srcs, v.rin,
            convb + o1, fusb + o1, convb + o1,
            convw + o1, buw + o1, convw + o1, RES, cN2);
        k_gemm_cat_ln<<<(cN2 + 63) / 64, 256, 0, stream>>>(RES, catW + o4, catb + o1,
                                                           lng + o1, lnb + o1,
                                                           out + (size_t)(cN0 + cN1) * D, cN2);
    }
}